// Round 3
// baseline (202.591 us; speedup 1.0000x reference)
//
#include <hip/hip_runtime.h>
#include <hip/hip_bf16.h>
#include <stdint.h>

#define M_DIM 8192
#define N_DIM 4096
#define K_DIM 4096

#define BM 256
#define BN 256
#define BK 64                 // bytes of K per LDS tile; 2 K-steps of 32 for mfma 32x32x32
#define NT (K_DIM / BK)       // 64 K-tiles
#define DEPTH 4               // circular LDS pipeline depth

typedef int v4i  __attribute__((ext_vector_type(4)));
typedef int v16i __attribute__((ext_vector_type(16)));

#define AS1C(p) ((const __attribute__((address_space(1))) void*)(p))
#define AS3(p)  ((__attribute__((address_space(3))) void*)(p))

// ---------------------------------------------------------------------------
// Fused pack pass: int32 (int8-range) -> int8 for BOTH operands, one launch.
// ---------------------------------------------------------------------------
__device__ __forceinline__ int pack4(int a, int b, int c, int d) {
  return (a & 0xff) | ((b & 0xff) << 8) | ((c & 0xff) << 16) | (d << 24);
}

__global__ void pack_both_kernel(const int* __restrict__ x, const int* __restrict__ w,
                                 char* __restrict__ A8, char* __restrict__ B8,
                                 int nA, int nTot) {
  int idx = blockIdx.x * blockDim.x + threadIdx.x;
  int stride = gridDim.x * blockDim.x;
  for (int i = idx; i < nTot; i += stride) {
    const int4* pin;
    int4* pout;
    if (i < nA) {
      pin  = (const int4*)x + 4 * (size_t)i;
      pout = (int4*)A8 + i;
    } else {
      int j = i - nA;
      pin  = (const int4*)w + 4 * (size_t)j;
      pout = (int4*)B8 + j;
    }
    int4 v0 = pin[0];
    int4 v1 = pin[1];
    int4 v2 = pin[2];
    int4 v3 = pin[3];
    int4 o;
    o.x = pack4(v0.x, v0.y, v0.z, v0.w);
    o.y = pack4(v1.x, v1.y, v1.z, v1.w);
    o.z = pack4(v2.x, v2.y, v2.z, v2.w);
    o.w = pack4(v3.x, v3.y, v3.z, v3.w);
    *pout = o;
  }
}

// ---------------------------------------------------------------------------
// int8 GEMM: 256x256 tile, 8 waves (2Mx4N, per-wave 128x64), BK=64B,
// mfma_i32_32x32x32_i8, 4-deep LDS circular pipeline, counted vmcnt (8/4/0),
// TWO phases per K-tile (one per K=32 step): {stage 2 gload_lds, 6 ds_read_b128,
// lgkm0, setprio, 8 MFMA}, one s_barrier per phase.  XCD swizzle, chunk-XOR
// LDS swizzle (0 conflicts measured R1/R2).
//
// Pipeline invariants:
//   ph0(t) top: own outstanding gloads = tiles t..t+2 (12). vmcnt(8) -> tile t
//   complete; barrier -> ALL waves' tile-t stages complete AND all waves'
//   ds_reads of tile t-1 drained (each wave's ph1(t-1) lgkm0 precedes it).
//   STAGE_A(t+3)/STAGE_B(t+3) overwrite buf[(t-1)&3]: safe per the above.
// ---------------------------------------------------------------------------
__global__ __launch_bounds__(512, 2) void gemm_i8_kernel(
    const char* __restrict__ A8, const char* __restrict__ B8,
    const int* __restrict__ bias, const float* __restrict__ alpha_p,
    const float* __restrict__ beta_p, int* __restrict__ out) {
  __shared__ alignas(16) char lds[DEPTH][BM * BK + BN * BK];  // 4 x 32 KiB

  const int tid  = threadIdx.x;
  const int lane = tid & 63;
  const int wave = tid >> 6;

  // XCD-aware bijective swizzle: 512 blocks, 64 consecutive per XCD.
  const int orig = blockIdx.x;
  const int swz  = (orig & 7) * (512 / 8) + (orig >> 3);
  const int bm   = (swz >> 4) * BM;  // 32 row-tiles
  const int bn   = (swz & 15) * BN;  // 16 col-tiles

  // Staging geometry: per operand tile 16 KB = 2 rounds x 512 thr x 16 B.
  // Pre-swizzled global chunk g = p ^ ((row>>1)&3) (both-sides swizzle).
  int aoff[2], boff[2], ldsoff[2];
#pragma unroll
  for (int i = 0; i < 2; ++i) {
    int linear = i * 8192 + tid * 16;
    int row = linear >> 6;           // 64 B rows
    int p   = (linear >> 4) & 3;
    int g   = p ^ ((row >> 1) & 3);
    ldsoff[i] = i * 8192 + wave * 1024;       // wave-uniform LDS base
    aoff[i] = (bm + row) * K_DIM + g * 16;
    boff[i] = (bn + row) * K_DIM + g * 16;
  }

#define STAGE_A(t)                                                                  \
  do {                                                                              \
    const char* ab_ = A8 + (t) * BK;                                                \
    char* base_ = &lds[(t) & (DEPTH - 1)][0];                                       \
    _Pragma("unroll") for (int i_ = 0; i_ < 2; ++i_)                                \
      __builtin_amdgcn_global_load_lds(AS1C(ab_ + aoff[i_]),                        \
                                       AS3(base_ + ldsoff[i_]), 16, 0, 0);          \
  } while (0)

#define STAGE_B(t)                                                                  \
  do {                                                                              \
    const char* bb_ = B8 + (t) * BK;                                                \
    char* base_ = &lds[(t) & (DEPTH - 1)][0];                                       \
    _Pragma("unroll") for (int i_ = 0; i_ < 2; ++i_)                                \
      __builtin_amdgcn_global_load_lds(AS1C(bb_ + boff[i_]),                        \
                                       AS3(base_ + 16384 + ldsoff[i_]), 16, 0, 0);  \
  } while (0)

  v16i acc[4][2];
#pragma unroll
  for (int i = 0; i < 4; ++i)
#pragma unroll
    for (int j = 0; j < 2; ++j)
#pragma unroll
      for (int r = 0; r < 16; ++r) acc[i][j][r] = 0;

  const int wr = wave >> 2;         // 0..1 (M half: 128 rows)
  const int wc = wave & 3;          // 0..3 (N quarter: 64 cols)
  const int l31   = lane & 31;
  const int khalf = lane >> 5;      // which 16-B K-chunk of the 32-B K-step
  const int kxor  = (l31 >> 1) & 3; // row-derived swizzle XOR (lane-only)

  // A-frag (32x32x32 i8): lane holds row l31, 16 contiguous K-bytes at
  // chunk (ks*2 + khalf); swizzled chunk' = chunk ^ kxor.
#define COMPUTE_KS(t, ks)                                                           \
  do {                                                                              \
    const char* base_ = &lds[(t) & (DEPTH - 1)][0];                                 \
    const char* As_ = base_;                                                        \
    const char* Bs_ = base_ + 16384;                                                \
    const int coff_ = ((((ks) * 2 + khalf) ^ kxor) << 4);                           \
    v4i bf0 = *(const v4i*)(Bs_ + (wc * 64 + 0 * 32 + l31) * 64 + coff_);           \
    v4i bf1 = *(const v4i*)(Bs_ + (wc * 64 + 1 * 32 + l31) * 64 + coff_);           \
    v4i af0 = *(const v4i*)(As_ + (wr * 128 + 0 * 32 + l31) * 64 + coff_);          \
    v4i af1 = *(const v4i*)(As_ + (wr * 128 + 1 * 32 + l31) * 64 + coff_);          \
    v4i af2 = *(const v4i*)(As_ + (wr * 128 + 2 * 32 + l31) * 64 + coff_);          \
    v4i af3 = *(const v4i*)(As_ + (wr * 128 + 3 * 32 + l31) * 64 + coff_);          \
    asm volatile("s_waitcnt lgkmcnt(0)" ::: "memory");                              \
    __builtin_amdgcn_s_setprio(1);                                                  \
    acc[0][0] = __builtin_amdgcn_mfma_i32_32x32x32_i8(af0, bf0, acc[0][0], 0, 0, 0);\
    acc[1][0] = __builtin_amdgcn_mfma_i32_32x32x32_i8(af1, bf0, acc[1][0], 0, 0, 0);\
    acc[2][0] = __builtin_amdgcn_mfma_i32_32x32x32_i8(af2, bf0, acc[2][0], 0, 0, 0);\
    acc[3][0] = __builtin_amdgcn_mfma_i32_32x32x32_i8(af3, bf0, acc[3][0], 0, 0, 0);\
    acc[0][1] = __builtin_amdgcn_mfma_i32_32x32x32_i8(af0, bf1, acc[0][1], 0, 0, 0);\
    acc[1][1] = __builtin_amdgcn_mfma_i32_32x32x32_i8(af1, bf1, acc[1][1], 0, 0, 0);\
    acc[2][1] = __builtin_amdgcn_mfma_i32_32x32x32_i8(af2, bf1, acc[2][1], 0, 0, 0);\
    acc[3][1] = __builtin_amdgcn_mfma_i32_32x32x32_i8(af3, bf1, acc[3][1], 0, 0, 0);\
    __builtin_amdgcn_s_setprio(0);                                                  \
  } while (0)

  // Prologue: fill 3 pipeline stages (12 outstanding gloads per thread).
  STAGE_A(0); STAGE_B(0);
  STAGE_A(1); STAGE_B(1);
  STAGE_A(2); STAGE_B(2);

  for (int t = 0; t < NT - 2; ++t) {
    // phase 0 (ks=0)
    asm volatile("s_waitcnt vmcnt(8) lgkmcnt(0)" ::: "memory");
    __builtin_amdgcn_s_barrier();
    if (t + 3 < NT) STAGE_A(t + 3);
    COMPUTE_KS(t, 0);
    // phase 1 (ks=1)
    __builtin_amdgcn_s_barrier();
    if (t + 3 < NT) STAGE_B(t + 3);
    COMPUTE_KS(t, 1);
  }
  // peeled tile NT-2
  asm volatile("s_waitcnt vmcnt(4) lgkmcnt(0)" ::: "memory");
  __builtin_amdgcn_s_barrier();
  COMPUTE_KS(NT - 2, 0);
  __builtin_amdgcn_s_barrier();
  COMPUTE_KS(NT - 2, 1);
  // peeled tile NT-1
  asm volatile("s_waitcnt vmcnt(0) lgkmcnt(0)" ::: "memory");
  __builtin_amdgcn_s_barrier();
  COMPUTE_KS(NT - 1, 0);
  __builtin_amdgcn_s_barrier();
  COMPUTE_KS(NT - 1, 1);

  // Epilogue: D = rint(alpha*acc + beta*bias[n]).
  // 32x32 C/D layout: col = lane&31, row = (reg&3) + 8*(reg>>2) + 4*(lane>>5).
  const float alpha = *alpha_p;
  const float beta  = *beta_p;
  const int col0 = bn + wc * 64 + l31;
  float bb2[2];
#pragma unroll
  for (int nj = 0; nj < 2; ++nj) bb2[nj] = beta * (float)bias[col0 + nj * 32];

  const int rbase = bm + wr * 128 + 4 * khalf;
#pragma unroll
  for (int mi = 0; mi < 4; ++mi) {
#pragma unroll
    for (int q = 0; q < 4; ++q) {
#pragma unroll
      for (int rr = 0; rr < 4; ++rr) {
        int reg = q * 4 + rr;
        size_t rowoff = (size_t)(rbase + mi * 32 + rr + 8 * q) * N_DIM;
#pragma unroll
        for (int nj = 0; nj < 2; ++nj) {
          out[rowoff + col0 + nj * 32] =
              (int)rintf(fmaf(alpha, (float)acc[mi][nj][reg], bb2[nj]));
        }
      }
    }
  }
#undef STAGE_A
#undef STAGE_B
#undef COMPUTE_KS
}

// ---------------------------------------------------------------------------
// Safety fallback if ws is too small for the packed operands (slow but right).
// ---------------------------------------------------------------------------
__global__ void naive_kernel(const int* __restrict__ x, const int* __restrict__ w,
                             const int* __restrict__ bias,
                             const float* __restrict__ alpha_p,
                             const float* __restrict__ beta_p,
                             int* __restrict__ out) {
  size_t idx = (size_t)blockIdx.x * 256 + threadIdx.x;
  int m = (int)(idx / N_DIM);
  int n = (int)(idx % N_DIM);
  const int4* xr = (const int4*)(x + (size_t)m * K_DIM);
  const int4* wr = (const int4*)(w + (size_t)n * K_DIM);
  int acc = 0;
  for (int k = 0; k < K_DIM / 4; ++k) {
    int4 a = xr[k];
    int4 b = wr[k];
    acc += a.x * b.x + a.y * b.y + a.z * b.z + a.w * b.w;
  }
  out[idx] = (int)rintf(fmaf(*alpha_p, (float)acc, (*beta_p) * (float)bias[n]));
}

extern "C" void kernel_launch(void* const* d_in, const int* in_sizes, int n_in,
                              void* d_out, int out_size, void* d_ws, size_t ws_size,
                              hipStream_t stream) {
  const int*   x     = (const int*)d_in[0];
  const int*   w     = (const int*)d_in[1];
  const int*   bias  = (const int*)d_in[2];
  const float* alpha = (const float*)d_in[3];
  const float* beta  = (const float*)d_in[4];
  int* out = (int*)d_out;

  const size_t a8_bytes = (size_t)M_DIM * K_DIM;  // 32 MiB
  const size_t b8_bytes = (size_t)N_DIM * K_DIM;  // 16 MiB

  if (ws_size >= a8_bytes + b8_bytes) {
    char* A8 = (char*)d_ws;
    char* B8 = A8 + a8_bytes;
    const int nA = (int)(a8_bytes / 16);
    const int nTot = (int)((a8_bytes + b8_bytes) / 16);
    pack_both_kernel<<<2048, 256, 0, stream>>>(x, w, A8, B8, nA, nTot);
    const int nblk = (M_DIM / BM) * (N_DIM / BN);  // 32*16 = 512
    gemm_i8_kernel<<<nblk, 512, 0, stream>>>(A8, B8, bias, alpha, beta, out);
  } else {
    naive_kernel<<<(M_DIM * (size_t)N_DIM) / 256, 256, 0, stream>>>(x, w, bias, alpha, beta, out);
  }
}

// Round 4
// 183.583 us; speedup vs baseline: 1.1035x; 1.1035x over previous
//
#include <hip/hip_runtime.h>
#include <hip/hip_bf16.h>
#include <stdint.h>

#define M_DIM 8192
#define N_DIM 4096
#define K_DIM 4096

#define BM 256
#define BN 256
#define BK 64                 // bytes of K per LDS tile = one mfma_i32_16x16x64_i8 K
#define NT (K_DIM / BK)       // 64 K-tiles
#define DEPTH 4               // circular LDS pipeline depth

typedef int v4i __attribute__((ext_vector_type(4)));

#define AS1C(p) ((const __attribute__((address_space(1))) void*)(p))
#define AS3(p)  ((__attribute__((address_space(3))) void*)(p))

// ---------------------------------------------------------------------------
// Fused pack pass: int32 (int8-range) -> int8 for BOTH operands, one launch.
// ---------------------------------------------------------------------------
__device__ __forceinline__ int pack4(int a, int b, int c, int d) {
  return (a & 0xff) | ((b & 0xff) << 8) | ((c & 0xff) << 16) | (d << 24);
}

__global__ void pack_both_kernel(const int* __restrict__ x, const int* __restrict__ w,
                                 char* __restrict__ A8, char* __restrict__ B8,
                                 int nA, int nTot) {
  int idx = blockIdx.x * blockDim.x + threadIdx.x;
  int stride = gridDim.x * blockDim.x;
  for (int i = idx; i < nTot; i += stride) {
    const int4* pin;
    int4* pout;
    if (i < nA) {
      pin  = (const int4*)x + 4 * (size_t)i;
      pout = (int4*)A8 + i;
    } else {
      int j = i - nA;
      pin  = (const int4*)w + 4 * (size_t)j;
      pout = (int4*)B8 + j;
    }
    int4 v0 = pin[0];
    int4 v1 = pin[1];
    int4 v2 = pin[2];
    int4 v3 = pin[3];
    int4 o;
    o.x = pack4(v0.x, v0.y, v0.z, v0.w);
    o.y = pack4(v1.x, v1.y, v1.z, v1.w);
    o.z = pack4(v2.x, v2.y, v2.z, v2.w);
    o.w = pack4(v3.x, v3.y, v3.z, v3.w);
    *pout = o;
  }
}

// ---------------------------------------------------------------------------
// int8 GEMM: 256x256 tile, 8 waves (2Mx4N, per-wave 128x64), BK=64B,
// mfma_i32_16x16x64_i8 (R1/R2-verified conflict-free fragment reads),
// 4-deep LDS circular pipeline, counted vmcnt (8/4/0), TWO phases per K-tile:
//   ph0: vmcnt(8)+lgkm0, barrier, STAGE_A(t+3), read bf[0..3]+af[0..3],
//        setprio { 16 MFMA (mi=0..3) }
//   ph1: barrier, STAGE_B(t+3), read af[4..7],
//        setprio { 16 MFMA (mi=4..7) }  (bf held in registers)
// Race safety: STAGE_*(t+3) overwrites buf[(t-1)&3]; every wave's reads of
// tile t-1 are drained by its ph0(t) lgkmcnt(0) before the ph0 barrier.
// ---------------------------------------------------------------------------
__global__ __launch_bounds__(512, 2) void gemm_i8_kernel(
    const char* __restrict__ A8, const char* __restrict__ B8,
    const int* __restrict__ bias, const float* __restrict__ alpha_p,
    const float* __restrict__ beta_p, int* __restrict__ out) {
  __shared__ alignas(16) char lds[DEPTH][BM * BK + BN * BK];  // 4 x 32 KiB

  const int tid  = threadIdx.x;
  const int lane = tid & 63;
  const int wave = tid >> 6;

  // XCD-aware bijective swizzle: 512 blocks, 64 consecutive per XCD.
  const int orig = blockIdx.x;
  const int swz  = (orig & 7) * (512 / 8) + (orig >> 3);
  const int bm   = (swz >> 4) * BM;  // 32 row-tiles
  const int bn   = (swz & 15) * BN;  // 16 col-tiles

  // Staging geometry: per operand tile 16 KB = 2 rounds x 512 thr x 16 B.
  // Pre-swizzled global chunk g = p ^ ((row>>1)&3) (both-sides swizzle).
  int aoff[2], boff[2], ldsoff[2];
#pragma unroll
  for (int i = 0; i < 2; ++i) {
    int linear = i * 8192 + tid * 16;
    int row = linear >> 6;           // 64 B rows
    int p   = (linear >> 4) & 3;
    int g   = p ^ ((row >> 1) & 3);
    ldsoff[i] = i * 8192 + wave * 1024;       // wave-uniform LDS base
    aoff[i] = (bm + row) * K_DIM + g * 16;
    boff[i] = (bn + row) * K_DIM + g * 16;
  }

#define STAGE_A(t)                                                                  \
  do {                                                                              \
    const char* ab_ = A8 + (t) * BK;                                                \
    char* base_ = &lds[(t) & (DEPTH - 1)][0];                                       \
    _Pragma("unroll") for (int i_ = 0; i_ < 2; ++i_)                                \
      __builtin_amdgcn_global_load_lds(AS1C(ab_ + aoff[i_]),                        \
                                       AS3(base_ + ldsoff[i_]), 16, 0, 0);          \
  } while (0)

#define STAGE_B(t)                                                                  \
  do {                                                                              \
    const char* bb_ = B8 + (t) * BK;                                                \
    char* base_ = &lds[(t) & (DEPTH - 1)][0];                                       \
    _Pragma("unroll") for (int i_ = 0; i_ < 2; ++i_)                                \
      __builtin_amdgcn_global_load_lds(AS1C(bb_ + boff[i_]),                        \
                                       AS3(base_ + 16384 + ldsoff[i_]), 16, 0, 0);  \
  } while (0)

  v4i acc[8][4];
#pragma unroll
  for (int i = 0; i < 8; ++i)
#pragma unroll
    for (int j = 0; j < 4; ++j) acc[i][j] = (v4i){0, 0, 0, 0};

  const int wr = wave >> 2;         // 0..1 (M half: 128 rows)
  const int wc = wave & 3;          // 0..3 (N quarter: 64 cols)
  const int frow = lane & 15;
  const int fchunk = lane >> 4;     // which 16B K-chunk this lane reads
  // swizzle XOR depends only on frow (rows differ by multiples of 16) -> lane-const
  const int swzoff = ((fchunk ^ ((frow >> 1) & 3)) << 4);

  // Prologue: fill 3 pipeline stages (12 outstanding gloads per thread).
  STAGE_A(0); STAGE_B(0);
  STAGE_A(1); STAGE_B(1);
  STAGE_A(2); STAGE_B(2);

#define PH0(t, DO_STAGE)                                                            \
  do {                                                                              \
    if (DO_STAGE) STAGE_A((t) + 3);                                                 \
    const char* base_ = &lds[(t) & (DEPTH - 1)][0];                                 \
    _Pragma("unroll") for (int nj = 0; nj < 4; ++nj) {                              \
      int r_ = wc * 64 + nj * 16 + frow;                                            \
      bf[nj] = *(const v4i*)(base_ + 16384 + r_ * 64 + swzoff);                     \
    }                                                                               \
    v4i af_[4];                                                                     \
    _Pragma("unroll") for (int mi = 0; mi < 4; ++mi) {                              \
      int r_ = wr * 128 + mi * 16 + frow;                                           \
      af_[mi] = *(const v4i*)(base_ + r_ * 64 + swzoff);                            \
    }                                                                               \
    __builtin_amdgcn_s_setprio(1);                                                  \
    _Pragma("unroll") for (int mi = 0; mi < 4; ++mi)                                \
      _Pragma("unroll") for (int nj = 0; nj < 4; ++nj)                              \
        acc[mi][nj] = __builtin_amdgcn_mfma_i32_16x16x64_i8(af_[mi], bf[nj],        \
                                                            acc[mi][nj], 0, 0, 0); \
    __builtin_amdgcn_s_setprio(0);                                                  \
  } while (0)

#define PH1(t, DO_STAGE)                                                            \
  do {                                                                              \
    if (DO_STAGE) STAGE_B((t) + 3);                                                 \
    const char* base_ = &lds[(t) & (DEPTH - 1)][0];                                 \
    v4i af_[4];                                                                     \
    _Pragma("unroll") for (int mi = 0; mi < 4; ++mi) {                              \
      int r_ = wr * 128 + (mi + 4) * 16 + frow;                                     \
      af_[mi] = *(const v4i*)(base_ + r_ * 64 + swzoff);                            \
    }                                                                               \
    __builtin_amdgcn_s_setprio(1);                                                  \
    _Pragma("unroll") for (int mi = 0; mi < 4; ++mi)                                \
      _Pragma("unroll") for (int nj = 0; nj < 4; ++nj)                              \
        acc[mi + 4][nj] = __builtin_amdgcn_mfma_i32_16x16x64_i8(af_[mi], bf[nj],    \
                                                            acc[mi + 4][nj],       \
                                                            0, 0, 0);              \
    __builtin_amdgcn_s_setprio(0);                                                  \
  } while (0)

  for (int t = 0; t < NT - 2; ++t) {
    v4i bf[4];
    asm volatile("s_waitcnt vmcnt(8) lgkmcnt(0)" ::: "memory");
    __builtin_amdgcn_s_barrier();
    PH0(t, t + 3 < NT);
    __builtin_amdgcn_s_barrier();
    PH1(t, t + 3 < NT);
  }
  {
    v4i bf[4];
    asm volatile("s_waitcnt vmcnt(4) lgkmcnt(0)" ::: "memory");
    __builtin_amdgcn_s_barrier();
    PH0(NT - 2, false);
    __builtin_amdgcn_s_barrier();
    PH1(NT - 2, false);
  }
  {
    v4i bf[4];
    asm volatile("s_waitcnt vmcnt(0) lgkmcnt(0)" ::: "memory");
    __builtin_amdgcn_s_barrier();
    PH0(NT - 1, false);
    __builtin_amdgcn_s_barrier();
    PH1(NT - 1, false);
  }

  // Epilogue: D = rint(alpha*acc + beta*bias[n]).
  // C/D layout (16x16): col = lane&15, row = (lane>>4)*4 + reg.
  const float alpha = *alpha_p;
  const float beta  = *beta_p;
  const int col0 = bn + wc * 64 + frow;
  float bb4[4];
#pragma unroll
  for (int nj = 0; nj < 4; ++nj) bb4[nj] = beta * (float)bias[col0 + nj * 16];

  const int rbase = bm + wr * 128 + (lane >> 4) * 4;
#pragma unroll
  for (int mi = 0; mi < 8; ++mi) {
#pragma unroll
    for (int r = 0; r < 4; ++r) {
      size_t rowoff = (size_t)(rbase + mi * 16 + r) * N_DIM;
#pragma unroll
      for (int nj = 0; nj < 4; ++nj) {
        out[rowoff + col0 + nj * 16] =
            (int)rintf(fmaf(alpha, (float)acc[mi][nj][r], bb4[nj]));
      }
    }
  }
#undef STAGE_A
#undef STAGE_B
#undef PH0
#undef PH1
}

// ---------------------------------------------------------------------------
// Safety fallback if ws is too small for the packed operands (slow but right).
// ---------------------------------------------------------------------------
__global__ void naive_kernel(const int* __restrict__ x, const int* __restrict__ w,
                             const int* __restrict__ bias,
                             const float* __restrict__ alpha_p,
                             const float* __restrict__ beta_p,
                             int* __restrict__ out) {
  size_t idx = (size_t)blockIdx.x * 256 + threadIdx.x;
  int m = (int)(idx / N_DIM);
  int n = (int)(idx % N_DIM);
  const int4* xr = (const int4*)(x + (size_t)m * K_DIM);
  const int4* wr = (const int4*)(w + (size_t)n * K_DIM);
  int acc = 0;
  for (int k = 0; k < K_DIM / 4; ++k) {
    int4 a = xr[k];
    int4 b = wr[k];
    acc += a.x * b.x + a.y * b.y + a.z * b.z + a.w * b.w;
  }
  out[idx] = (int)rintf(fmaf(*alpha_p, (float)acc, (*beta_p) * (float)bias[n]));
}

extern "C" void kernel_launch(void* const* d_in, const int* in_sizes, int n_in,
                              void* d_out, int out_size, void* d_ws, size_t ws_size,
                              hipStream_t stream) {
  const int*   x     = (const int*)d_in[0];
  const int*   w     = (const int*)d_in[1];
  const int*   bias  = (const int*)d_in[2];
  const float* alpha = (const float*)d_in[3];
  const float* beta  = (const float*)d_in[4];
  int* out = (int*)d_out;

  const size_t a8_bytes = (size_t)M_DIM * K_DIM;  // 32 MiB
  const size_t b8_bytes = (size_t)N_DIM * K_DIM;  // 16 MiB

  if (ws_size >= a8_bytes + b8_bytes) {
    char* A8 = (char*)d_ws;
    char* B8 = A8 + a8_bytes;
    const int nA = (int)(a8_bytes / 16);
    const int nTot = (int)((a8_bytes + b8_bytes) / 16);
    pack_both_kernel<<<2048, 256, 0, stream>>>(x, w, A8, B8, nA, nTot);
    const int nblk = (M_DIM / BM) * (N_DIM / BN);  // 32*16 = 512
    gemm_i8_kernel<<<nblk, 512, 0, stream>>>(A8, B8, bias, alpha, beta, out);
  } else {
    naive_kernel<<<(M_DIM * (size_t)N_DIM) / 256, 256, 0, stream>>>(x, w, bias, alpha, beta, out);
  }
}